// Round 1
// baseline (338.527 us; speedup 1.0000x reference)
//
#include <hip/hip_runtime.h>

// NonMaxSuppression: 3x3 local max + thr>=0.6 + 10px border, output ordered (y,x) coords.
// Shapes fixed by the reference: (16,1,1536,1536) fp32.
#define W 1536
#define H 1536
#define NB 16
#define N (NB * H * W)                      // 37748736
#define BLOCK 256
#define PIX_PER_THREAD 8
#define PIX_PER_BLOCK (BLOCK * PIX_PER_THREAD)  // 2048
#define NBLK (N / PIX_PER_BLOCK)                // 18432
#define NCHUNK (N / 64)                         // 589824 uint64 ballot masks
#define CHUNKS_PER_BLOCK (PIX_PER_BLOCK / 64)   // 32
#define REP_THR 0.6f

// Pass 1: predicate -> per-wave ballot masks + per-block survivor counts.
__global__ __launch_bounds__(BLOCK) void nms_pass1(const float* __restrict__ in,
                                                   unsigned long long* __restrict__ masks,
                                                   unsigned int* __restrict__ counts) {
    const unsigned int t = threadIdx.x;
    const unsigned int lane = t & 63u;
    const unsigned int wave = t >> 6;
    const unsigned int base = blockIdx.x * PIX_PER_BLOCK;
    __shared__ unsigned int wc[BLOCK / 64];
    unsigned int cnt = 0;
#pragma unroll
    for (int j = 0; j < PIX_PER_THREAD; ++j) {
        unsigned int i = base + (unsigned int)j * BLOCK + t;
        unsigned int xx = i % (unsigned int)W;
        unsigned int yy = (i / (unsigned int)W) % (unsigned int)H;
        bool p = false;
        if (xx >= 10u && xx < (unsigned int)(W - 10) && yy >= 10u && yy < (unsigned int)(H - 10)) {
            float v = in[i];
            if (v >= REP_THR) {
                p = (in[i - W - 1] <= v) & (in[i - W] <= v) & (in[i - W + 1] <= v) &
                    (in[i - 1] <= v) & (in[i + 1] <= v) &
                    (in[i + W - 1] <= v) & (in[i + W] <= v) & (in[i + W + 1] <= v);
            }
        }
        unsigned long long m = __ballot(p);
        if (lane == 0) {
            masks[blockIdx.x * CHUNKS_PER_BLOCK + (unsigned int)j * (BLOCK / 64) + wave] = m;
            cnt += (unsigned int)__popcll(m);
        }
    }
    if (lane == 0) wc[wave] = cnt;
    __syncthreads();
    if (t == 0) {
        unsigned int s = 0;
#pragma unroll
        for (int w = 0; w < BLOCK / 64; ++w) s += wc[w];
        counts[blockIdx.x] = s;
    }
}

// Pass 2: single-block exclusive scan of NBLK per-block counts.
__global__ __launch_bounds__(1024) void nms_scan(const unsigned int* __restrict__ counts,
                                                 unsigned int* __restrict__ offsets, int n) {
    __shared__ unsigned int buf[1024];
    __shared__ unsigned int carry;
    if (threadIdx.x == 0) carry = 0;
    __syncthreads();
    for (int start = 0; start < n; start += 1024) {
        int idx = start + (int)threadIdx.x;
        unsigned int v = (idx < n) ? counts[idx] : 0u;
        buf[threadIdx.x] = v;
        __syncthreads();
        for (int off = 1; off < 1024; off <<= 1) {
            unsigned int tv = (threadIdx.x >= (unsigned int)off) ? buf[threadIdx.x - off] : 0u;
            __syncthreads();
            buf[threadIdx.x] += tv;
            __syncthreads();
        }
        unsigned int incl = buf[threadIdx.x];
        if (idx < n) offsets[idx] = carry + incl - v;
        __syncthreads();
        if (threadIdx.x == 1023) carry += incl;
        __syncthreads();
    }
}

// Pass 3: replay masks, compute ordered positions, scatter (y, x).
__global__ __launch_bounds__(BLOCK) void nms_pass3(const unsigned long long* __restrict__ masks,
                                                   const unsigned int* __restrict__ offsets,
                                                   int* __restrict__ out, unsigned int K) {
    const unsigned int t = threadIdx.x;
    const unsigned int lane = t & 63u;
    const unsigned int wave = t >> 6;
    __shared__ unsigned int coff[CHUNKS_PER_BLOCK];
    if (t < CHUNKS_PER_BLOCK)
        coff[t] = (unsigned int)__popcll(masks[blockIdx.x * CHUNKS_PER_BLOCK + t]);
    __syncthreads();
    if (t == 0) {
        unsigned int r = 0;
#pragma unroll
        for (int k = 0; k < CHUNKS_PER_BLOCK; ++k) {
            unsigned int c = coff[k];
            coff[k] = r;
            r += c;
        }
    }
    __syncthreads();
    const unsigned int blockBase = offsets[blockIdx.x];
    const unsigned int base = blockIdx.x * PIX_PER_BLOCK;
#pragma unroll
    for (int j = 0; j < PIX_PER_THREAD; ++j) {
        unsigned int chunk = (unsigned int)j * (BLOCK / 64) + wave;
        unsigned long long m = masks[blockIdx.x * CHUNKS_PER_BLOCK + chunk];
        if ((m >> lane) & 1ull) {
            unsigned int local = (unsigned int)__popcll(m & ((1ull << lane) - 1ull));
            unsigned int pos = blockBase + coff[chunk] + local;
            unsigned int i = base + (unsigned int)j * BLOCK + t;
            unsigned int xx = i % (unsigned int)W;
            unsigned int yy = (i / (unsigned int)W) % (unsigned int)H;
            if (pos < K) {
                out[pos] = (int)yy;
                out[K + pos] = (int)xx;
            }
        }
    }
}

extern "C" void kernel_launch(void* const* d_in, const int* in_sizes, int n_in,
                              void* d_out, int out_size, void* d_ws, size_t ws_size,
                              hipStream_t stream) {
    const float* in = (const float*)d_in[0];
    int* out = (int*)d_out;
    unsigned long long* masks = (unsigned long long*)d_ws;
    unsigned int* counts = (unsigned int*)((char*)d_ws + (size_t)NCHUNK * 8);
    unsigned int* offsets = counts + NBLK;
    const unsigned int K = (unsigned int)(out_size / 2);

    nms_pass1<<<NBLK, BLOCK, 0, stream>>>(in, masks, counts);
    nms_scan<<<1, 1024, 0, stream>>>(counts, offsets, NBLK);
    nms_pass3<<<NBLK, BLOCK, 0, stream>>>(masks, offsets, out, K);
}

// Round 2
// 259.829 us; speedup vs baseline: 1.3029x; 1.3029x over previous
//
#include <hip/hip_runtime.h>

// NonMaxSuppression: 3x3 local max + thr>=0.6 + 10px border, output ordered (y,x) coords.
// Shapes fixed by the reference: (16,1,1536,1536) fp32.
#define W 1536
#define H 1536
#define NB 16
#define N (NB * H * W)                 // 37748736
#define T_PX 16                        // pixels per thread (1536 % 16 == 0: runs never straddle rows)
#define BLOCK 256
#define PX_PER_BLOCK (BLOCK * T_PX)    // 4096
#define NBLK (N / PX_PER_BLOCK)        // 9216 = 1024 * 9
#define REP_THR 0.6f

// Pass 1: each thread evaluates 16 consecutive x-pixels via 18 float4 loads (3 rows x 24 cols),
// emits a 16-bit predicate mask (bit j <-> pixel s+j, flat order preserved) + per-block count.
__global__ __launch_bounds__(BLOCK) void nms_pass1(const float* __restrict__ in,
                                                   unsigned short* __restrict__ masks,
                                                   unsigned int* __restrict__ counts) {
    const unsigned t = threadIdx.x;
    const unsigned gid = blockIdx.x * BLOCK + t;
    const unsigned s = gid * T_PX;
    const unsigned row = s / W;          // b*H + y
    const unsigned yy = row % H;
    const unsigned x0 = s - row * W;
    unsigned bits = 0u;
    if (yy >= 10u && yy < (unsigned)(H - 10)) {
        const float* p = in + s;
        float r0[24], r1[24], r2[24];
#pragma unroll
        for (int k = 0; k < 6; ++k) {
            *(float4*)(r0 + 4 * k) = *(const float4*)(p - W - 4 + 4 * k);
            *(float4*)(r1 + 4 * k) = *(const float4*)(p - 4 + 4 * k);
            *(float4*)(r2 + 4 * k) = *(const float4*)(p + W - 4 + 4 * k);
        }
#pragma unroll
        for (int j = 0; j < T_PX; ++j) {
            float v = r1[j + 4];
            float m = fmaxf(fmaxf(r0[j + 3], r0[j + 4]), r0[j + 5]);   // v_max3
            m = fmaxf(m, fmaxf(r1[j + 3], r1[j + 5]));
            float m2 = fmaxf(fmaxf(r2[j + 3], r2[j + 4]), r2[j + 5]);  // v_max3
            m = fmaxf(fmaxf(m, m2), REP_THR);
            bits |= (v >= m) ? (1u << j) : 0u;
        }
        // x-border: valid x in [10, 1526)
        unsigned vmask = 0xFFFFu;
        if (x0 == 0u) vmask = 0xFC00u;                 // j >= 10
        else if (x0 == (unsigned)(W - T_PX)) vmask = 0x003Fu;  // j <= 5
        bits &= vmask;
    }
    masks[gid] = (unsigned short)bits;
    unsigned cnt = __popc(bits);
#pragma unroll
    for (int o = 32; o > 0; o >>= 1) cnt += __shfl_down(cnt, o, 64);
    __shared__ unsigned wsum[BLOCK / 64];
    if ((t & 63u) == 0u) wsum[t >> 6] = cnt;
    __syncthreads();
    if (t == 0) counts[blockIdx.x] = wsum[0] + wsum[1] + wsum[2] + wsum[3];
}

// Pass 2: single-block one-pass scan of NBLK=9216 counts (1024 threads x 9 each).
__global__ __launch_bounds__(1024) void nms_scan(const unsigned int* __restrict__ counts,
                                                 unsigned int* __restrict__ offsets) {
    const int t = threadIdx.x;
    const int lane = t & 63, wv = t >> 6;  // 16 waves
    unsigned v[9];
    unsigned sum = 0;
#pragma unroll
    for (int k = 0; k < 9; ++k) { v[k] = counts[t * 9 + k]; sum += v[k]; }
    unsigned incl = sum;
#pragma unroll
    for (int o = 1; o < 64; o <<= 1) {
        unsigned u = __shfl_up(incl, o, 64);
        if (lane >= o) incl += u;
    }
    __shared__ unsigned wtot[16];
    if (lane == 63) wtot[wv] = incl;
    __syncthreads();
    unsigned wbase = 0;
#pragma unroll
    for (int k = 0; k < 16; ++k) wbase += (k < wv) ? wtot[k] : 0u;
    unsigned base = wbase + incl - sum;  // exclusive prefix for this thread's 9 entries
#pragma unroll
    for (int k = 0; k < 9; ++k) { offsets[t * 9 + k] = base; base += v[k]; }
}

// Pass 3: replay 16-bit masks, block-wide shuffle scan for ordered positions, scatter (y, x).
__global__ __launch_bounds__(BLOCK) void nms_pass3(const unsigned short* __restrict__ masks,
                                                   const unsigned int* __restrict__ offsets,
                                                   int* __restrict__ out, unsigned int K) {
    const unsigned t = threadIdx.x;
    const unsigned lane = t & 63u, wv = t >> 6;
    const unsigned gid = blockIdx.x * BLOCK + t;
    unsigned bits = masks[gid];
    const unsigned cnt = __popc(bits);
    unsigned incl = cnt;
#pragma unroll
    for (int o = 1; o < 64; o <<= 1) {
        unsigned u = __shfl_up(incl, o, 64);
        if (lane >= o) incl += u;
    }
    __shared__ unsigned wtot[BLOCK / 64];
    if (lane == 63u) wtot[wv] = incl;
    __syncthreads();
    unsigned wbase = 0;
#pragma unroll
    for (int k = 0; k < BLOCK / 64; ++k) wbase += (k < wv) ? wtot[k] : 0u;
    unsigned pos = offsets[blockIdx.x] + wbase + incl - cnt;
    if (bits) {
        const unsigned s = gid * T_PX;
        const unsigned row = s / W;
        const int yy = (int)(row % H);
        const int x0 = (int)(s - row * W);
        while (bits) {
            int j = __builtin_ctz(bits);
            bits &= bits - 1u;
            if (pos < K) {
                out[pos] = yy;
                out[K + pos] = x0 + j;
            }
            ++pos;
        }
    }
}

extern "C" void kernel_launch(void* const* d_in, const int* in_sizes, int n_in,
                              void* d_out, int out_size, void* d_ws, size_t ws_size,
                              hipStream_t stream) {
    const float* in = (const float*)d_in[0];
    int* out = (int*)d_out;
    unsigned short* masks = (unsigned short*)d_ws;                       // N/16 u16 = 4.72 MB
    unsigned int* counts = (unsigned int*)((char*)d_ws + (size_t)(N / T_PX) * 2);
    unsigned int* offsets = counts + NBLK;
    const unsigned int K = (unsigned int)(out_size / 2);

    nms_pass1<<<NBLK, BLOCK, 0, stream>>>(in, masks, counts);
    nms_scan<<<1, 1024, 0, stream>>>(counts, offsets);
    nms_pass3<<<NBLK, BLOCK, 0, stream>>>(masks, offsets, out, K);
}